// Round 8
// baseline (502.450 us; speedup 1.0000x reference)
//
#include <hip/hip_runtime.h>

// ---------------------------------------------------------------------------
// MHSA bf16-MFMA pipeline v8: B=2, S=2048, D=1024, H=16, HD=64
//   p:  fused prep (z=0: W_qkv^T, z=1: W_out^T, z=2: x f32->bf16)
//   k1: qkv GEMM (128x128, global_load_lds); Q (pre-scaled log2e/8) + K ->
//       qk_bf [4096][2048]; V -> vT[bh][d][t] in epilogue
//   k2: flash attention: ONE wave per block (no barriers at all), 64 q rows
//       per wave, K/V double-buffered in padded LDS (stride 72 -> conflict-
//       free), reg-staged with tile+2 global prefetch. S^T x32, PV x16
//       register-direct, l via ones-MFMA.
//   k3: out GEMM 64x128 tiles -> f32
// Frag layouts (m89/m91): x32: A[m=l16][k=quad*8+j], B[k=quad*8+j][n=l16];
// x16: A[m=l16][k=quad*4+j], B[k=quad*4+j][n=l16]; C: col=l16, row=quad*4+i.
// ws (48 MB): Wout_t 0-2 | qk_bf 2-18 | vT 18-26 | attn_b 26-34 |
//             x_bf 34-42 | Wqkv_t 42-48
// ---------------------------------------------------------------------------

typedef short bf16x8 __attribute__((ext_vector_type(8)));
typedef short bf16x4 __attribute__((ext_vector_type(4)));
typedef float f32x4 __attribute__((ext_vector_type(4)));

#if __has_builtin(__builtin_amdgcn_mfma_f32_16x16x16_bf16)
#define MFMA16(a, b, c) __builtin_amdgcn_mfma_f32_16x16x16_bf16(a, b, c, 0, 0, 0)
#else
#define MFMA16(a, b, c) __builtin_amdgcn_mfma_f32_16x16x16bf16_1k(a, b, c, 0, 0, 0)
#endif
#define MFMA32(a, b, c) __builtin_amdgcn_mfma_f32_16x16x32_bf16(a, b, c, 0, 0, 0)

__device__ __forceinline__ unsigned short f2bf(float f) {   // RNE
  unsigned u = __float_as_uint(f);
  u = (u + 0x7fffu + ((u >> 16) & 1u)) >> 16;
  return (unsigned short)u;
}
__device__ __forceinline__ unsigned pack_bf2(float lo, float hi) {
  unsigned a = __float_as_uint(lo) + 0x8000u;
  unsigned b = __float_as_uint(hi) + 0x8000u;
  return __builtin_amdgcn_perm(b, a, 0x07060302);
}
__device__ __forceinline__ void load_lds16(const unsigned short* g, unsigned short* l) {
  __builtin_amdgcn_global_load_lds(
      (const __attribute__((address_space(1))) void*)g,
      (__attribute__((address_space(3))) void*)l, 16, 0, 0);
}

// --- p: fused prep ---------------------------------------------------------
__global__ __launch_bounds__(256) void prep(
    const float* __restrict__ x, unsigned short* __restrict__ x_bf,
    const float* __restrict__ W_qkv, unsigned short* __restrict__ Wqkv_t,
    const float* __restrict__ W_out, unsigned short* __restrict__ Wout_t)
{
  const int tid = threadIdx.x;
  if (blockIdx.z == 2) {
    const int bid = blockIdx.y * 48 + blockIdx.x;          // 0..767
    const int n = 4096 * 1024;
    for (int i = bid * 2048 + tid * 8; i < n; i += 768 * 2048) {
      float4 f0 = *(const float4*)(x + i);
      float4 f1 = *(const float4*)(x + i + 4);
      union { unsigned short u[8]; uint4 v; } pk;
      pk.u[0] = f2bf(f0.x); pk.u[1] = f2bf(f0.y); pk.u[2] = f2bf(f0.z); pk.u[3] = f2bf(f0.w);
      pk.u[4] = f2bf(f1.x); pk.u[5] = f2bf(f1.y); pk.u[6] = f2bf(f1.z); pk.u[7] = f2bf(f1.w);
      *(uint4*)(x_bf + i) = pk.v;
    }
    return;
  }
  const float* in = (blockIdx.z == 0) ? W_qkv : W_out;
  unsigned short* out = (blockIdx.z == 0) ? Wqkv_t : Wout_t;
  const int R = 1024;
  const int C = (blockIdx.z == 0) ? 3072 : 1024;
  const int c0 = blockIdx.x * 64;
  if (c0 >= C) return;
  __shared__ float tile[64][65];
  const int r0 = blockIdx.y * 64;
  {
    const int rr = tid >> 4;
    const int cc = (tid & 15) * 4;
#pragma unroll
    for (int it = 0; it < 4; ++it) {
      float4 f = *(const float4*)&in[(size_t)(r0 + rr + 16 * it) * C + c0 + cc];
      tile[rr + 16 * it][cc + 0] = f.x;
      tile[rr + 16 * it][cc + 1] = f.y;
      tile[rr + 16 * it][cc + 2] = f.z;
      tile[rr + 16 * it][cc + 3] = f.w;
    }
  }
  __syncthreads();
  {
    const int cr = tid >> 2;
    const int rk = (tid & 3) * 16;
    union { unsigned short u[16]; uint4 v[2]; } pk;
#pragma unroll
    for (int j = 0; j < 16; ++j) pk.u[j] = f2bf(tile[rk + j][cr]);
    uint4* dst = (uint4*)&out[(size_t)(c0 + cr) * R + r0 + rk];
    dst[0] = pk.v[0];
    dst[1] = pk.v[1];
  }
}

// --- k1: qkv GEMM 128x128 --------------------------------------------------
__global__ __launch_bounds__(256) void gemm_qkv(
    const unsigned short* __restrict__ A,    // x_bf [4096][1024]
    const unsigned short* __restrict__ Bt,   // Wqkv_t [3072][1024]
    const float* __restrict__ bias,
    unsigned short* __restrict__ qkc,        // qk_bf [4096][2048]
    unsigned short* __restrict__ vT)         // [32][64][2048]
{
  __shared__ unsigned short As[128][32];
  __shared__ unsigned short Bs[128][32];
  const int tid = threadIdx.x;
  const int wave = tid >> 6, lane = tid & 63;
  const int l16 = lane & 15, quad = lane >> 4;
  const int m0 = blockIdx.y * 128, n0 = blockIdx.x * 128;
  const int wm = (wave & 1) * 64, wn = (wave >> 1) * 64;
  const int lr = lane >> 2;
  const int lc = (lane & 3) * 8;
  const int K = 1024;

  f32x4 acc[4][4] = {};

  for (int k0 = 0; k0 < K; k0 += 32) {
    __syncthreads();
    load_lds16(&A [(size_t)(m0 + 16 * wave + lr) * K + k0 + lc],      &As[16 * wave][0]);
    load_lds16(&A [(size_t)(m0 + 64 + 16 * wave + lr) * K + k0 + lc], &As[64 + 16 * wave][0]);
    load_lds16(&Bt[(size_t)(n0 + 16 * wave + lr) * K + k0 + lc],      &Bs[16 * wave][0]);
    load_lds16(&Bt[(size_t)(n0 + 64 + 16 * wave + lr) * K + k0 + lc], &Bs[64 + 16 * wave][0]);
    __syncthreads();

    bf16x8 af[4], bfr[4];
#pragma unroll
    for (int mi = 0; mi < 4; ++mi)
      af[mi] = *(const bf16x8*)&As[wm + 16 * mi + l16][quad * 8];
#pragma unroll
    for (int ni = 0; ni < 4; ++ni)
      bfr[ni] = *(const bf16x8*)&Bs[wn + 16 * ni + l16][quad * 8];
#pragma unroll
    for (int mi = 0; mi < 4; ++mi)
#pragma unroll
      for (int ni = 0; ni < 4; ++ni)
        acc[mi][ni] = MFMA32(af[mi], bfr[ni], acc[mi][ni]);
  }

  const float SCQ = 0.18033688f;   // log2(e)/sqrt(64), folded into Q
#pragma unroll
  for (int ni = 0; ni < 4; ++ni) {
    const int colb = n0 + wn + 16 * ni;
    const int col = colb + l16;
    const float bv = bias[col];
    if (colb < 1024) {                 // Q: pre-scale for exp2 softmax
#pragma unroll
      for (int mi = 0; mi < 4; ++mi)
#pragma unroll
        for (int i = 0; i < 4; ++i) {
          const int row = m0 + wm + 16 * mi + quad * 4 + i;
          qkc[(size_t)row * 2048 + col] = f2bf((acc[mi][ni][i] + bv) * SCQ);
        }
    } else if (colb < 2048) {          // K
#pragma unroll
      for (int mi = 0; mi < 4; ++mi)
#pragma unroll
        for (int i = 0; i < 4; ++i) {
          const int row = m0 + wm + 16 * mi + quad * 4 + i;
          qkc[(size_t)row * 2048 + col] = f2bf(acc[mi][ni][i] + bv);
        }
    } else {                           // V -> vT[bh][d][t], packed pairs in t
      const int h = (col - 2048) >> 6, d = col & 63;
#pragma unroll
      for (int mi = 0; mi < 4; ++mi) {
        const int row = m0 + wm + 16 * mi + quad * 4;   // +i, i=0..3
        const int bb = row >> 11, t = row & 2047;
        unsigned short* dst = &vT[((size_t)(bb * 16 + h) * 64 + d) * 2048 + t];
        *(unsigned*)(dst)     = pack_bf2(acc[mi][ni][0] + bv, acc[mi][ni][1] + bv);
        *(unsigned*)(dst + 2) = pack_bf2(acc[mi][ni][2] + bv, acc[mi][ni][3] + bv);
      }
    }
  }
}

// --- k2: flash attention, 1-wave blocks, no barriers -----------------------
// Block = 1 wave = 64 q rows (s0 + 16mt + l16, mt 0..3), all 2048 keys.
// K/V tiles (64x64) double-buffered in padded LDS (row stride 72 shorts ->
// conflict-free b128/b64 access). Staging: global->VGPR (tile t+2 prefetch)
// -> ds_write (tile t+1) while computing tile t. In-order DS pipe makes
// write->read ordering free; no __syncthreads anywhere.
__global__ __launch_bounds__(64, 1) void attn_mfma(
    const unsigned short* __restrict__ qk,    // [4096][2048] (Q|K)
    const unsigned short* __restrict__ vT,    // [32][64][2048]
    unsigned short* __restrict__ attn_out)    // [4096][1024]
{
  __shared__ unsigned short Ks[2][4608];   // 64 rows x 72 (pad)
  __shared__ unsigned short Vs[2][4608];

  const int lane = threadIdx.x;
  const int l16 = lane & 15, quad = lane >> 4;
  const int bh = blockIdx.y, b = bh >> 4, h = bh & 15;
  const int s0 = blockIdx.x * 64;

  const unsigned short* qb = qk + (size_t)(b * 2048) * 2048 + h * 64;
  const unsigned short* kb = qb + 1024;
  const unsigned short* vb = vT + (size_t)bh * 64 * 2048;

  // staging geometry: lane covers rows srow+8j (j=0..7), 16B chunk lane&7
  const int srow = lane >> 3;
  const int sc = (lane & 7) * 8;
  const unsigned short* kg = kb + (size_t)srow * 2048 + sc;
  const unsigned short* vg = vb + (size_t)srow * 2048 + sc;
  const int wbase = srow * 72 + sc;

  uint4 kr[8], vr[8];
#pragma unroll
  for (int j = 0; j < 8; ++j) {
    kr[j] = *(const uint4*)(kg + (size_t)(8 * j) * 2048);
    vr[j] = *(const uint4*)(vg + (size_t)(8 * j) * 2048);
  }
#pragma unroll
  for (int j = 0; j < 8; ++j) {
    *(uint4*)&Ks[0][wbase + j * 576] = kr[j];
    *(uint4*)&Vs[0][wbase + j * 576] = vr[j];
  }
#pragma unroll
  for (int j = 0; j < 8; ++j) {          // tile 1 -> regs (in flight)
    kr[j] = *(const uint4*)(kg + (size_t)(64 + 8 * j) * 2048);
    vr[j] = *(const uint4*)(vg + 64 + (size_t)(8 * j) * 2048);
  }

  // Q frags (x32 B-layout: k=d, n=q); Q pre-scaled by log2e/8
  bf16x8 qf[4][2];
#pragma unroll
  for (int mt = 0; mt < 4; ++mt)
#pragma unroll
    for (int ks = 0; ks < 2; ++ks)
      qf[mt][ks] = *(const bf16x8*)&qb[(size_t)(s0 + 16 * mt + l16) * 2048 + 32 * ks + quad * 8];

  f32x4 O[4][4] = {};      // O^T accum: [mt][nd], C col=q=l16, row=d local
  f32x4 lacc[4] = {};      // l via ones-MFMA (rows replicated)
  const bf16x4 ones4 = {(short)0x3F80, (short)0x3F80, (short)0x3F80, (short)0x3F80};

  for (int it = 0; it < 32; ++it) {
    const int cur = it & 1;

    // ---- K frags (x32 A-layout: m=t, k=d) ----
    bf16x8 kf[4][2];
#pragma unroll
    for (int nt = 0; nt < 4; ++nt) {
      const int rb = (16 * nt + l16) * 72;
      kf[nt][0] = *(const bf16x8*)&Ks[cur][rb + quad * 8];
      kf[nt][1] = *(const bf16x8*)&Ks[cur][rb + 32 + quad * 8];
    }

    // ---- S^T = K Q^T (x32): C row=t=quad*4+i, col=q=l16 ----
    f32x4 sf[4][4];
#pragma unroll
    for (int nt = 0; nt < 4; ++nt)
#pragma unroll
      for (int mt = 0; mt < 4; ++mt) {
        f32x4 c = {0.0f, 0.0f, 0.0f, 0.0f};
        c = MFMA32(kf[nt][0], qf[mt][0], c);
        c = MFMA32(kf[nt][1], qf[mt][1], c);
        sf[nt][mt] = c;
      }

    // ---- V frags (x16 A-layout: m=d, k=t chunk c) ----
    bf16x4 vf[4][4];
#pragma unroll
    for (int nd = 0; nd < 4; ++nd) {
      const int rb = (16 * nd + l16) * 72;
#pragma unroll
      for (int c = 0; c < 4; ++c)
        vf[nd][c] = *(const bf16x4*)&Vs[cur][rb + c * 16 + quad * 4];
    }

    // ---- stage tile it+1 (regs -> other buffer); prefetch tile it+2 ----
    if (it < 31) {
#pragma unroll
      for (int j = 0; j < 8; ++j) {
        *(uint4*)&Ks[cur ^ 1][wbase + j * 576] = kr[j];
        *(uint4*)&Vs[cur ^ 1][wbase + j * 576] = vr[j];
      }
      if (it < 30) {
        const size_t t0 = (size_t)(it + 2) * 64;
#pragma unroll
        for (int j = 0; j < 8; ++j) {
          kr[j] = *(const uint4*)(kg + (t0 + 8 * j) * 2048);
          vr[j] = *(const uint4*)(vg + t0 + (size_t)(8 * j) * 2048);
        }
      }
    }

    // ---- p = exp2(s); pack to x16 B-frags (C-layout == B-frag identity) ----
    bf16x4 pp[4][4];
#pragma unroll
    for (int mt = 0; mt < 4; ++mt)
#pragma unroll
      for (int nt = 0; nt < 4; ++nt) {
        const float p0 = __builtin_amdgcn_exp2f(sf[nt][mt][0]);
        const float p1 = __builtin_amdgcn_exp2f(sf[nt][mt][1]);
        const float p2 = __builtin_amdgcn_exp2f(sf[nt][mt][2]);
        const float p3 = __builtin_amdgcn_exp2f(sf[nt][mt][3]);
        uint2 w;
        w.x = pack_bf2(p0, p1);
        w.y = pack_bf2(p2, p3);
        pp[mt][nt] = *(bf16x4*)&w;
      }

    // ---- O^T += V^T P^T (x16); l += ones P^T ----
#pragma unroll
    for (int c = 0; c < 4; ++c)
#pragma unroll
      for (int mt = 0; mt < 4; ++mt) {
        lacc[mt] = MFMA16(ones4, pp[mt][c], lacc[mt]);
#pragma unroll
        for (int nd = 0; nd < 4; ++nd)
          O[mt][nd] = MFMA16(vf[nd][c], pp[mt][c], O[mt][nd]);
      }
  }

  // ---- epilogue: lane holds q=s0+16mt+l16, d=16nd+quad*4+{0..3} ----
#pragma unroll
  for (int mt = 0; mt < 4; ++mt) {
    const float inv = 1.0f / lacc[mt][0];
    const size_t row = (size_t)(b * 2048 + s0 + 16 * mt + l16);
#pragma unroll
    for (int nd = 0; nd < 4; ++nd) {
      uint2 w;
      w.x = pack_bf2(O[mt][nd][0] * inv, O[mt][nd][1] * inv);
      w.y = pack_bf2(O[mt][nd][2] * inv, O[mt][nd][3] * inv);
      *(uint2*)&attn_out[row * 1024 + h * 64 + 16 * nd + quad * 4] = w;
    }
  }
}

// --- k3: out GEMM, 64x128 tiles (512 blocks = 2/CU) ------------------------
__global__ __launch_bounds__(256) void gemm_out(
    const unsigned short* __restrict__ A,    // attn_b [4096][1024]
    const unsigned short* __restrict__ Bt,   // Wout_t [1024][1024]
    const float* __restrict__ bias,
    float* __restrict__ C)                   // [4096][1024]
{
  __shared__ unsigned short As[64][32];
  __shared__ unsigned short Bs[128][32];
  const int tid = threadIdx.x;
  const int wave = tid >> 6, lane = tid & 63;
  const int l16 = lane & 15, quad = lane >> 4;
  const int m0 = blockIdx.y * 64, n0 = blockIdx.x * 128;
  const int wn = wave * 32;
  const int lr = lane >> 2;
  const int lc = (lane & 3) * 8;

  f32x4 acc[4][2] = {};

  for (int k0 = 0; k0 < 1024; k0 += 32) {
    __syncthreads();
    load_lds16(&A [(size_t)(m0 + 16 * wave + lr) * 1024 + k0 + lc],      &As[16 * wave][0]);
    load_lds16(&Bt[(size_t)(n0 + 32 * wave + lr) * 1024 + k0 + lc],      &Bs[32 * wave][0]);
    load_lds16(&Bt[(size_t)(n0 + 32 * wave + 16 + lr) * 1024 + k0 + lc], &Bs[32 * wave + 16][0]);
    __syncthreads();

    bf16x8 af[4], bfr[2];
#pragma unroll
    for (int mi = 0; mi < 4; ++mi)
      af[mi] = *(const bf16x8*)&As[16 * mi + l16][quad * 8];
#pragma unroll
    for (int ni = 0; ni < 2; ++ni)
      bfr[ni] = *(const bf16x8*)&Bs[wn + 16 * ni + l16][quad * 8];
#pragma unroll
    for (int mi = 0; mi < 4; ++mi)
#pragma unroll
      for (int ni = 0; ni < 2; ++ni)
        acc[mi][ni] = MFMA32(af[mi], bfr[ni], acc[mi][ni]);
  }

#pragma unroll
  for (int ni = 0; ni < 2; ++ni) {
    const int col = n0 + wn + 16 * ni + l16;
    const float bv = bias[col];
#pragma unroll
    for (int mi = 0; mi < 4; ++mi)
#pragma unroll
      for (int i = 0; i < 4; ++i) {
        const int row = m0 + 16 * mi + quad * 4 + i;
        C[(size_t)row * 1024 + col] = acc[mi][ni][i] + bv;
      }
  }
}

extern "C" void kernel_launch(void* const* d_in, const int* in_sizes, int n_in,
                              void* d_out, int out_size, void* d_ws, size_t ws_size,
                              hipStream_t stream) {
  const float* x     = (const float*)d_in[0];
  const float* W_qkv = (const float*)d_in[1];
  const float* b_qkv = (const float*)d_in[2];
  const float* W_out = (const float*)d_in[3];
  const float* b_out = (const float*)d_in[4];
  float* out = (float*)d_out;

  char* ws = (char*)d_ws;
  const size_t MB = 1048576;
  unsigned short* Wout_t = (unsigned short*)(ws);             //  0-2 MB
  unsigned short* qk_bf  = (unsigned short*)(ws + 2 * MB);    //  2-18 MB
  unsigned short* vT     = (unsigned short*)(ws + 18 * MB);   // 18-26 MB
  unsigned short* attn_b = (unsigned short*)(ws + 26 * MB);   // 26-34 MB
  unsigned short* x_bf   = (unsigned short*)(ws + 34 * MB);   // 34-42 MB
  unsigned short* Wqkv_t = (unsigned short*)(ws + 42 * MB);   // 42-48 MB

  prep<<<dim3(48, 16, 3), 256, 0, stream>>>(x, x_bf, W_qkv, Wqkv_t, W_out, Wout_t);

  gemm_qkv<<<dim3(24, 32), 256, 0, stream>>>(x_bf, Wqkv_t, b_qkv, qk_bf, vT);
  attn_mfma<<<dim3(32, 32), 64, 0, stream>>>(qk_bf, vT, attn_b);
  gemm_out<<<dim3(8, 64), 256, 0, stream>>>(attn_b, Wout_t, b_out, out);
}

// Round 9
// 197.362 us; speedup vs baseline: 2.5458x; 2.5458x over previous
//
#include <hip/hip_runtime.h>

// ---------------------------------------------------------------------------
// MHSA bf16-MFMA pipeline v9: B=2, S=2048, D=1024, H=16, HD=64
//   p:  fused prep (z=0: W_qkv^T, z=1: W_out^T, z=2: x f32->bf16)
//   k1: gemm_qkv (128x128, global_load_lds); Q (pre-scaled log2e/8) + K ->
//       qk_bf [4096][2048]; V -> per-wave LDS transpose -> coalesced
//       dwordx4 stores into vT[bh][d][t]
//   k2: flash attention (r7-proven): 4 waves, reg->LDS staged K/V double
//       buffer (no vmcnt drain at barriers), S^T x32, PV x16 register-direct,
//       l via ones-MFMA
//   k3: gemm_out 64x128 tiles -> f32
// Frag layouts (m89/m91): x32: A[m=l16][k=quad*8+j], B[k=quad*8+j][n=l16];
// x16: A[m=l16][k=quad*4+j], B[k=quad*4+j][n=l16]; C: col=l16, row=quad*4+i.
// ws (48 MB): Wout_t 0-2 | qk_bf 2-18 | vT 18-26 | attn_b 26-34 |
//             x_bf 34-42 | Wqkv_t 42-48
// ---------------------------------------------------------------------------

typedef short bf16x8 __attribute__((ext_vector_type(8)));
typedef short bf16x4 __attribute__((ext_vector_type(4)));
typedef float f32x4 __attribute__((ext_vector_type(4)));

#if __has_builtin(__builtin_amdgcn_mfma_f32_16x16x16_bf16)
#define MFMA16(a, b, c) __builtin_amdgcn_mfma_f32_16x16x16_bf16(a, b, c, 0, 0, 0)
#else
#define MFMA16(a, b, c) __builtin_amdgcn_mfma_f32_16x16x16bf16_1k(a, b, c, 0, 0, 0)
#endif
#define MFMA32(a, b, c) __builtin_amdgcn_mfma_f32_16x16x32_bf16(a, b, c, 0, 0, 0)

__device__ __forceinline__ unsigned short f2bf(float f) {   // RNE
  unsigned u = __float_as_uint(f);
  u = (u + 0x7fffu + ((u >> 16) & 1u)) >> 16;
  return (unsigned short)u;
}
__device__ __forceinline__ unsigned pack_bf2(float lo, float hi) {
  unsigned a = __float_as_uint(lo) + 0x8000u;
  unsigned b = __float_as_uint(hi) + 0x8000u;
  return __builtin_amdgcn_perm(b, a, 0x07060302);
}
__device__ __forceinline__ void load_lds16(const unsigned short* g, unsigned short* l) {
  __builtin_amdgcn_global_load_lds(
      (const __attribute__((address_space(1))) void*)g,
      (__attribute__((address_space(3))) void*)l, 16, 0, 0);
}

// --- p: fused prep ---------------------------------------------------------
__global__ __launch_bounds__(256) void prep(
    const float* __restrict__ x, unsigned short* __restrict__ x_bf,
    const float* __restrict__ W_qkv, unsigned short* __restrict__ Wqkv_t,
    const float* __restrict__ W_out, unsigned short* __restrict__ Wout_t)
{
  const int tid = threadIdx.x;
  if (blockIdx.z == 2) {
    const int bid = blockIdx.y * 48 + blockIdx.x;          // 0..767
    const int n = 4096 * 1024;
    for (int i = bid * 2048 + tid * 8; i < n; i += 768 * 2048) {
      float4 f0 = *(const float4*)(x + i);
      float4 f1 = *(const float4*)(x + i + 4);
      union { unsigned short u[8]; uint4 v; } pk;
      pk.u[0] = f2bf(f0.x); pk.u[1] = f2bf(f0.y); pk.u[2] = f2bf(f0.z); pk.u[3] = f2bf(f0.w);
      pk.u[4] = f2bf(f1.x); pk.u[5] = f2bf(f1.y); pk.u[6] = f2bf(f1.z); pk.u[7] = f2bf(f1.w);
      *(uint4*)(x_bf + i) = pk.v;
    }
    return;
  }
  const float* in = (blockIdx.z == 0) ? W_qkv : W_out;
  unsigned short* out = (blockIdx.z == 0) ? Wqkv_t : Wout_t;
  const int R = 1024;
  const int C = (blockIdx.z == 0) ? 3072 : 1024;
  const int c0 = blockIdx.x * 64;
  if (c0 >= C) return;
  __shared__ float tile[64][65];
  const int r0 = blockIdx.y * 64;
  {
    const int rr = tid >> 4;
    const int cc = (tid & 15) * 4;
#pragma unroll
    for (int it = 0; it < 4; ++it) {
      float4 f = *(const float4*)&in[(size_t)(r0 + rr + 16 * it) * C + c0 + cc];
      tile[rr + 16 * it][cc + 0] = f.x;
      tile[rr + 16 * it][cc + 1] = f.y;
      tile[rr + 16 * it][cc + 2] = f.z;
      tile[rr + 16 * it][cc + 3] = f.w;
    }
  }
  __syncthreads();
  {
    const int cr = tid >> 2;
    const int rk = (tid & 3) * 16;
    union { unsigned short u[16]; uint4 v[2]; } pk;
#pragma unroll
    for (int j = 0; j < 16; ++j) pk.u[j] = f2bf(tile[rk + j][cr]);
    uint4* dst = (uint4*)&out[(size_t)(c0 + cr) * R + r0 + rk];
    dst[0] = pk.v[0];
    dst[1] = pk.v[1];
  }
}

// --- k1: qkv GEMM 128x128; V transposed via per-wave LDS -------------------
__global__ __launch_bounds__(256) void gemm_qkv(
    const unsigned short* __restrict__ A,    // x_bf [4096][1024]
    const unsigned short* __restrict__ Bt,   // Wqkv_t [3072][1024]
    const float* __restrict__ bias,
    unsigned short* __restrict__ qkc,        // qk_bf [4096][2048]
    unsigned short* __restrict__ vT)         // [32][64][2048]
{
  __shared__ unsigned short As[128][32];
  __shared__ unsigned short Bs[128][32];
  __shared__ unsigned short VwAll[4][64 * 72];   // per-wave V transpose buf
  const int tid = threadIdx.x;
  const int wave = tid >> 6, lane = tid & 63;
  const int l16 = lane & 15, quad = lane >> 4;
  const int m0 = blockIdx.y * 128, n0 = blockIdx.x * 128;
  const int wm = (wave & 1) * 64, wn = (wave >> 1) * 64;
  const int lr = lane >> 2;
  const int lc = (lane & 3) * 8;
  const int K = 1024;

  f32x4 acc[4][4] = {};

  for (int k0 = 0; k0 < K; k0 += 32) {
    __syncthreads();
    load_lds16(&A [(size_t)(m0 + 16 * wave + lr) * K + k0 + lc],      &As[16 * wave][0]);
    load_lds16(&A [(size_t)(m0 + 64 + 16 * wave + lr) * K + k0 + lc], &As[64 + 16 * wave][0]);
    load_lds16(&Bt[(size_t)(n0 + 16 * wave + lr) * K + k0 + lc],      &Bs[16 * wave][0]);
    load_lds16(&Bt[(size_t)(n0 + 64 + 16 * wave + lr) * K + k0 + lc], &Bs[64 + 16 * wave][0]);
    __syncthreads();

    bf16x8 af[4], bfr[4];
#pragma unroll
    for (int mi = 0; mi < 4; ++mi)
      af[mi] = *(const bf16x8*)&As[wm + 16 * mi + l16][quad * 8];
#pragma unroll
    for (int ni = 0; ni < 4; ++ni)
      bfr[ni] = *(const bf16x8*)&Bs[wn + 16 * ni + l16][quad * 8];
#pragma unroll
    for (int mi = 0; mi < 4; ++mi)
#pragma unroll
      for (int ni = 0; ni < 4; ++ni)
        acc[mi][ni] = MFMA32(af[mi], bfr[ni], acc[mi][ni]);
  }

  const float SCQ = 0.18033688f;   // log2(e)/sqrt(64), folded into Q
  if (n0 < 2048) {                 // ---- Q / K blocks: row-major stores ----
#pragma unroll
    for (int ni = 0; ni < 4; ++ni) {
      const int colb = n0 + wn + 16 * ni;
      const int col = colb + l16;
      const float bv = bias[col];
      const float sc = (colb < 1024) ? SCQ : 1.0f;
#pragma unroll
      for (int mi = 0; mi < 4; ++mi)
#pragma unroll
        for (int i = 0; i < 4; ++i) {
          const int row = m0 + wm + 16 * mi + quad * 4 + i;
          qkc[(size_t)row * 2048 + col] = f2bf((acc[mi][ni][i] + bv) * sc);
        }
    }
  } else {                         // ---- V blocks: LDS transpose, coalesced
    unsigned short* Vw = &VwAll[wave][0];
#pragma unroll
    for (int ni = 0; ni < 4; ++ni) {
      const float bv = bias[n0 + wn + 16 * ni + l16];
#pragma unroll
      for (int mi = 0; mi < 4; ++mi) {
        uint2 w;
        w.x = pack_bf2(acc[mi][ni][0] + bv, acc[mi][ni][1] + bv);
        w.y = pack_bf2(acc[mi][ni][2] + bv, acc[mi][ni][3] + bv);
        // Vw[d = 16ni+l16][t_loc = 16mi + quad*4 .. +3]
        *(uint2*)&Vw[(16 * ni + l16) * 72 + 16 * mi + quad * 4] = w;
      }
    }
    // stream out: vT[(bb*16+h0)*64 + d][t0g + t], coalesced 16B/lane
    const int h0 = (n0 + wn - 2048) >> 6;
    const int bb = m0 >> 11;
    const int t0g = (m0 + wm) & 2047;
    unsigned short* vdst = vT + (size_t)(bb * 16 + h0) * 64 * 2048;
    const int dr = lane >> 3;          // +8j
    const int tc = (lane & 7) * 8;
#pragma unroll
    for (int j = 0; j < 8; ++j) {
      const int d = 8 * j + dr;
      uint4 v = *(const uint4*)&Vw[d * 72 + tc];
      *(uint4*)&vdst[(size_t)d * 2048 + t0g + tc] = v;
    }
  }
}

// --- k2: flash attention (r7-proven), reg->LDS staged K/V ------------------
// Block = 4 waves; wave w: q rows [bx*128 + 32w, +32), all 2048 keys.
// K,V tiles (64x64 bf16) double-buffered in LDS; staging goes global->VGPR
// (issued one iter ahead) -> ds_write, so the per-iter barrier drains only
// lgkmcnt. XOR chunk swizzle (chunk c of row r at c ^ (r&7)). S^T = K Q^T
// (x32); PV: O^T = V^T P^T (x16) register-direct; l via ones-MFMA.
__global__ __launch_bounds__(256, 2) void attn_mfma(
    const unsigned short* __restrict__ qk,    // [4096][2048] (Q|K)
    const unsigned short* __restrict__ vT,    // [32][64][2048]
    unsigned short* __restrict__ attn_out)    // [4096][1024]
{
  __shared__ unsigned short Ks[2][4096];
  __shared__ unsigned short Vs[2][4096];

  const int tid = threadIdx.x;
  const int wave = tid >> 6, lane = tid & 63;
  const int l16 = lane & 15, quad = lane >> 4;
  const int bh = blockIdx.y, b = bh >> 4, h = bh & 15;
  const int s0 = blockIdx.x * 128 + wave * 32;

  const unsigned short* qb = qk + (size_t)(b * 2048) * 2048 + h * 64;
  const unsigned short* kb = qb + 1024;
  const unsigned short* vb = vT + (size_t)bh * 64 * 2048;

  const int srow = lane >> 3;                     // 0..7
  const int schunk = ((lane & 7) ^ srow) * 8;     // swizzled 16B chunk
  const int r0a = wave * 16;
  const unsigned short* kg0 = kb + (size_t)(r0a + srow) * 2048 + schunk;
  const unsigned short* kg1 = kg0 + (size_t)8 * 2048;
  const unsigned short* vg0 = vb + (size_t)(r0a + srow) * 2048 + schunk;
  const unsigned short* vg1 = vg0 + (size_t)8 * 2048;
  const int wd0 = r0a * 64 + lane * 8;            // LDS dst (shorts)
  const int wd1 = (r0a + 8) * 64 + lane * 8;

  uint4 kr0 = *(const uint4*)(kg0);
  uint4 kr1 = *(const uint4*)(kg1);
  uint4 vr0 = *(const uint4*)(vg0);
  uint4 vr1 = *(const uint4*)(vg1);
  *(uint4*)&Ks[0][wd0] = kr0;  *(uint4*)&Ks[0][wd1] = kr1;
  *(uint4*)&Vs[0][wd0] = vr0;  *(uint4*)&Vs[0][wd1] = vr1;
  kr0 = *(const uint4*)(kg0 + (size_t)64 * 2048);
  kr1 = *(const uint4*)(kg1 + (size_t)64 * 2048);
  vr0 = *(const uint4*)(vg0 + 64);
  vr1 = *(const uint4*)(vg1 + 64);

  bf16x8 qf[2][2];
#pragma unroll
  for (int mt = 0; mt < 2; ++mt)
#pragma unroll
    for (int ks = 0; ks < 2; ++ks)
      qf[mt][ks] = *(const bf16x8*)&qb[(size_t)(s0 + 16 * mt + l16) * 2048 + 32 * ks + quad * 8];

  f32x4 O[2][4] = {};
  f32x4 lacc[2] = {};
  const bf16x4 ones4 = {(short)0x3F80, (short)0x3F80, (short)0x3F80, (short)0x3F80};
  const int sw = l16 & 7;
  const int h2 = quad >> 1, h1 = (quad & 1) * 4;

  __syncthreads();

  for (int it = 0; it < 32; ++it) {
    const int cur = it & 1;

    bf16x8 kf[4][2];
#pragma unroll
    for (int nt = 0; nt < 4; ++nt) {
      const int rb = (16 * nt + l16) * 64;
      kf[nt][0] = *(const bf16x8*)&Ks[cur][rb + ((quad ^ sw) * 8)];
      kf[nt][1] = *(const bf16x8*)&Ks[cur][rb + (((4 + quad) ^ sw) * 8)];
    }

    f32x4 sf[4][2];
#pragma unroll
    for (int nt = 0; nt < 4; ++nt)
#pragma unroll
      for (int mt = 0; mt < 2; ++mt) {
        f32x4 c = {0.0f, 0.0f, 0.0f, 0.0f};
        c = MFMA32(kf[nt][0], qf[mt][0], c);
        c = MFMA32(kf[nt][1], qf[mt][1], c);
        sf[nt][mt] = c;
      }

    if (it < 31) {
      *(uint4*)&Ks[cur ^ 1][wd0] = kr0;
      *(uint4*)&Ks[cur ^ 1][wd1] = kr1;
      *(uint4*)&Vs[cur ^ 1][wd0] = vr0;
      *(uint4*)&Vs[cur ^ 1][wd1] = vr1;
      if (it < 30) {
        const size_t ko = (size_t)(it + 2) * 64 * 2048;
        kr0 = *(const uint4*)(kg0 + ko);
        kr1 = *(const uint4*)(kg1 + ko);
        vr0 = *(const uint4*)(vg0 + (it + 2) * 64);
        vr1 = *(const uint4*)(vg1 + (it + 2) * 64);
      }
    }

    bf16x4 vf[4][4];
#pragma unroll
    for (int nd = 0; nd < 4; ++nd) {
      const int rb = (16 * nd + l16) * 64;
#pragma unroll
      for (int c = 0; c < 4; ++c)
        vf[nd][c] = *(const bf16x4*)&Vs[cur][rb + (((2 * c + h2) ^ sw) * 8 + h1)];
    }

    bf16x4 pp[2][4];
#pragma unroll
    for (int mt = 0; mt < 2; ++mt)
#pragma unroll
      for (int nt = 0; nt < 4; ++nt) {
        const float p0 = __builtin_amdgcn_exp2f(sf[nt][mt][0]);
        const float p1 = __builtin_amdgcn_exp2f(sf[nt][mt][1]);
        const float p2 = __builtin_amdgcn_exp2f(sf[nt][mt][2]);
        const float p3 = __builtin_amdgcn_exp2f(sf[nt][mt][3]);
        uint2 w;
        w.x = pack_bf2(p0, p1);
        w.y = pack_bf2(p2, p3);
        pp[mt][nt] = *(bf16x4*)&w;
      }

#pragma unroll
    for (int c = 0; c < 4; ++c)
#pragma unroll
      for (int mt = 0; mt < 2; ++mt) {
        lacc[mt] = MFMA16(ones4, pp[mt][c], lacc[mt]);
#pragma unroll
        for (int nd = 0; nd < 4; ++nd)
          O[mt][nd] = MFMA16(vf[nd][c], pp[mt][c], O[mt][nd]);
      }

    __syncthreads();
  }

#pragma unroll
  for (int mt = 0; mt < 2; ++mt) {
    const float inv = 1.0f / lacc[mt][0];
    const size_t row = (size_t)(b * 2048 + s0 + 16 * mt + l16);
#pragma unroll
    for (int nd = 0; nd < 4; ++nd) {
      uint2 w;
      w.x = pack_bf2(O[mt][nd][0] * inv, O[mt][nd][1] * inv);
      w.y = pack_bf2(O[mt][nd][2] * inv, O[mt][nd][3] * inv);
      *(uint2*)&attn_out[row * 1024 + h * 64 + 16 * nd + quad * 4] = w;
    }
  }
}

// --- k3: out GEMM, 64x128 tiles (512 blocks = 2/CU) ------------------------
__global__ __launch_bounds__(256) void gemm_out(
    const unsigned short* __restrict__ A,    // attn_b [4096][1024]
    const unsigned short* __restrict__ Bt,   // Wout_t [1024][1024]
    const float* __restrict__ bias,
    float* __restrict__ C)                   // [4096][1024]
{
  __shared__ unsigned short As[64][32];
  __shared__ unsigned short Bs[128][32];
  const int tid = threadIdx.x;
  const int wave = tid >> 6, lane = tid & 63;
  const int l16 = lane & 15, quad = lane >> 4;
  const int m0 = blockIdx.y * 64, n0 = blockIdx.x * 128;
  const int wn = wave * 32;
  const int lr = lane >> 2;
  const int lc = (lane & 3) * 8;

  f32x4 acc[4][2] = {};

  for (int k0 = 0; k0 < 1024; k0 += 32) {
    __syncthreads();
    load_lds16(&A [(size_t)(m0 + 16 * wave + lr) * 1024 + k0 + lc],      &As[16 * wave][0]);
    load_lds16(&Bt[(size_t)(n0 + 32 * wave + lr) * 1024 + k0 + lc],      &Bs[32 * wave][0]);
    load_lds16(&Bt[(size_t)(n0 + 32 * wave + 16 + lr) * 1024 + k0 + lc], &Bs[32 * wave + 16][0]);
    __syncthreads();

    bf16x8 af[4], bfr[2];
#pragma unroll
    for (int mi = 0; mi < 4; ++mi)
      af[mi] = *(const bf16x8*)&As[16 * mi + l16][quad * 8];
#pragma unroll
    for (int ni = 0; ni < 2; ++ni)
      bfr[ni] = *(const bf16x8*)&Bs[wn + 16 * ni + l16][quad * 8];
#pragma unroll
    for (int mi = 0; mi < 4; ++mi)
#pragma unroll
      for (int ni = 0; ni < 2; ++ni)
        acc[mi][ni] = MFMA32(af[mi], bfr[ni], acc[mi][ni]);
  }

#pragma unroll
  for (int ni = 0; ni < 2; ++ni) {
    const int col = n0 + wn + 16 * ni + l16;
    const float bv = bias[col];
#pragma unroll
    for (int mi = 0; mi < 4; ++mi)
#pragma unroll
      for (int i = 0; i < 4; ++i) {
        const int row = m0 + 16 * mi + quad * 4 + i;
        C[(size_t)row * 1024 + col] = acc[mi][ni][i] + bv;
      }
  }
}

extern "C" void kernel_launch(void* const* d_in, const int* in_sizes, int n_in,
                              void* d_out, int out_size, void* d_ws, size_t ws_size,
                              hipStream_t stream) {
  const float* x     = (const float*)d_in[0];
  const float* W_qkv = (const float*)d_in[1];
  const float* b_qkv = (const float*)d_in[2];
  const float* W_out = (const float*)d_in[3];
  const float* b_out = (const float*)d_in[4];
  float* out = (float*)d_out;

  char* ws = (char*)d_ws;
  const size_t MB = 1048576;
  unsigned short* Wout_t = (unsigned short*)(ws);             //  0-2 MB
  unsigned short* qk_bf  = (unsigned short*)(ws + 2 * MB);    //  2-18 MB
  unsigned short* vT     = (unsigned short*)(ws + 18 * MB);   // 18-26 MB
  unsigned short* attn_b = (unsigned short*)(ws + 26 * MB);   // 26-34 MB
  unsigned short* x_bf   = (unsigned short*)(ws + 34 * MB);   // 34-42 MB
  unsigned short* Wqkv_t = (unsigned short*)(ws + 42 * MB);   // 42-48 MB

  prep<<<dim3(48, 16, 3), 256, 0, stream>>>(x, x_bf, W_qkv, Wqkv_t, W_out, Wout_t);

  gemm_qkv<<<dim3(24, 32), 256, 0, stream>>>(x_bf, Wqkv_t, b_qkv, qk_bf, vT);
  attn_mfma<<<dim3(16, 32), 256, 0, stream>>>(qk_bf, vT, attn_b);
  gemm_out<<<dim3(8, 64), 256, 0, stream>>>(attn_b, Wout_t, b_out, out);
}